// Round 16
// baseline (32.025 us; speedup 1.0000x reference)
//
#include <hip/hip_runtime.h>

// Problem constants (from setup_inputs): B=8, N=1024, E=16384, Din=128, U=128
#define B_   8
#define N_   1024
#define E_   16384
#define DIN_ 128
#define U_   128
#define CAP_ 64     // bucket capacity per node; deg ~ Poisson(16), P(>64) ~ 1e-20

// ---------------------------------------------------------------------------
// Node 1: zero degree counters (B*N = 8192 ints = 32 KB). Tiny. Needed as a
// separate node so k_mix's fill blocks (which can't order against sibling
// GEMM blocks) see zeroed counters.
__global__ __launch_bounds__(256) void k_zero(int* __restrict__ counts) {
    counts[blockIdx.x * 256 + threadIdx.x] = 0;    // 32 blocks x 256
}

// ---------------------------------------------------------------------------
// Node 2: heterogeneous mix — SINGLE CHANGE vs r15: support & fill run in one
// node so fill's atomic/memory latency hides under the GEMM's VALU/LDS work.
// Blocks 0..511: r11-exact GEMM (16 rows/block, minus counts zeroing).
// Blocks 512..1023: r11-exact edge fill. XCD map preserved for both halves
// (bid&7 == batch in each range; 512 % 8 == 0).
__global__ __launch_bounds__(256) void k_mix(
    const float* __restrict__ x, const float* __restrict__ kern,
    float* __restrict__ support,
    const int* __restrict__ edge_index, const int* __restrict__ edge_mask,
    int* __restrict__ counts, unsigned short* __restrict__ bucket) {
    __shared__ float xs[16][DIN_];                  // 8 KB (GEMM path only)
    const int tid = threadIdx.x;

    if (blockIdx.x < 512) {
        // ---------------- GEMM path (r11-exact body) -----------------------
        const int bid = blockIdx.x;
        const int u = tid & 127;
        const int h = tid >> 7;                     // 0/1: rows h*8 .. h*8+7
        const int bb = bid & 7;                     // batch -> XCD bb
        const int rc = bid >> 3;                    // row chunk 0..63
        const int row0 = bb * N_ + rc * 16;
        const float4* xsrc = (const float4*)(x + (size_t)row0 * DIN_);
        #pragma unroll
        for (int i = 0; i < 2; ++i)                 // 512 float4 = 16x128
            ((float4*)xs)[i * 256 + tid] = xsrc[i * 256 + tid];
        __syncthreads();
        float acc[8] = {0.f,0.f,0.f,0.f,0.f,0.f,0.f,0.f};
        #pragma unroll 4
        for (int d = 0; d < DIN_; ++d) {
            float k = kern[d * U_ + u];             // coalesced, L2-resident
            #pragma unroll
            for (int r = 0; r < 8; ++r) acc[r] = fmaf(xs[h*8+r][d], k, acc[r]);
        }
        #pragma unroll
        for (int r = 0; r < 8; ++r)
            support[(size_t)(row0 + h*8 + r) * U_ + u] = acc[r];
    } else {
        // ---------------- fill path (r11-exact body) -----------------------
        const int bid   = blockIdx.x - 512;
        const int b     = bid & 7;                  // batch -> XCD b
        const int chunk = bid >> 3;                 // 0..63
        const int e     = chunk * 256 + tid;        // edge within batch
        if (edge_mask[(size_t)b * E_ + e] != 0) {
            const int* p = edge_index + (size_t)b * 2 * E_;
            int src = min(max(p[e], 0), N_ - 1);
            int dst = min(max(p[E_ + e], 0), N_ - 1);
            int bn = b * N_ + dst;
            int pos = atomicAdd(&counts[bn], 1);
            if (pos < CAP_) bucket[(size_t)bn * CAP_ + pos] = (unsigned short)src;
        }
    }
}

// ---------------------------------------------------------------------------
// Node 3 (byte-identical to r15): per-node aggregation, 64 lanes x float2
// channels per node, 4 nodes/block, 2048 blocks, LDS weight-precompute +
// ds_read_b64 broadcast loop. XCD swizzle: block bi -> batch (bi&7).
__global__ __launch_bounds__(256) void k_agg(
    const float* __restrict__ support, const int* __restrict__ node_mask,
    const int* __restrict__ counts, const unsigned short* __restrict__ bucket,
    const float* __restrict__ bias, float* __restrict__ out) {
    const int bi   = blockIdx.x;                    // 0..2047
    const int lane = threadIdx.x & 63;              // float2 channel pair
    const int g    = threadIdx.x >> 6;              // node within block 0..3
    const int bn   = (bi & 7) * N_ + (bi >> 3) * 4 + g;  // batch-major
    const int b    = bn >> 10;                      // / N_

    __shared__ int2 sp[4][CAP_];                    // {global row, isd_m bits}

    int nm = node_mask[bn];
    int cnt_true = counts[bn];
    int cnt = min(cnt_true, CAP_);
    float isd_n = rsqrtf(fmaxf((float)cnt_true + (nm ? 1.0f : 0.0f), 1e-6f));

    if (lane < cnt) {                               // parallel weight precompute
        int m  = bucket[(size_t)bn * CAP_ + lane];  // coalesced 128B/wave
        int gm = b * N_ + m;
        float w = rsqrtf(fmaxf((float)counts[gm] + (node_mask[gm] ? 1.0f : 0.0f), 1e-6f));
        sp[g][lane] = make_int2(gm, __float_as_int(w));
    }
    __syncthreads();

    const float2* supp2 = (const float2*)support;
    float2 bs = ((const float2*)bias)[lane];
    float2 acc = make_float2(0.f, 0.f);
    if (nm) {                                       // self-loop
        float2 s = supp2[(size_t)bn * 64 + lane];
        acc.x = isd_n * s.x; acc.y = isd_n * s.y;
    }
    #pragma unroll 4
    for (int t = 0; t < cnt; ++t) {
        int2 p = sp[g][t];                          // ds_read_b64 broadcast
        float w = __int_as_float(p.y);
        float2 s = supp2[(size_t)p.x * 64 + lane];  // 512B/wave, XCD-local L2
        acc.x = fmaf(w, s.x, acc.x);
        acc.y = fmaf(w, s.y, acc.y);
    }
    float2 o;
    o.x = nm ? fmaf(isd_n, acc.x, bs.x) : 0.f;
    o.y = nm ? fmaf(isd_n, acc.y, bs.y) : 0.f;
    ((float2*)out)[(size_t)bn * 64 + lane] = o;
}

// ---------------------------------------------------------------------------
extern "C" void kernel_launch(void* const* d_in, const int* in_sizes, int n_in,
                              void* d_out, int out_size, void* d_ws, size_t ws_size,
                              hipStream_t stream) {
    const float* x         = (const float*)d_in[0];
    const int*   node_mask = (const int*)d_in[1];
    const int*   edge_index= (const int*)d_in[2];
    const int*   edge_mask = (const int*)d_in[3];
    const float* kern      = (const float*)d_in[4];
    const float* bias      = (const float*)d_in[5];
    float*       out       = (float*)d_out;

    char* ws = (char*)d_ws;
    size_t off = 0;
    float*          support = (float*)(ws + off);          off += (size_t)B_ * N_ * U_ * sizeof(float);
    int*            counts  = (int*)(ws + off);            off += (size_t)B_ * N_ * sizeof(int);
    unsigned short* bucket  = (unsigned short*)(ws + off); off += (size_t)B_ * N_ * CAP_ * sizeof(unsigned short);

    k_zero<<<B_ * N_ / 256, 256, 0, stream>>>(counts);
    k_mix<<<1024, 256, 0, stream>>>(x, kern, support, edge_index, edge_mask,
                                    counts, bucket);
    k_agg<<<B_ * N_ / 4, 256, 0, stream>>>(support, node_mask, counts, bucket, bias, out);
}

// Round 17
// 30.842 us; speedup vs baseline: 1.0383x; 1.0383x over previous
//
#include <hip/hip_runtime.h>

// ==================== r11-EXACT + OVERHEAD PROBE NODE =======================
// r11 (29.0 us, best known) byte-identical, plus one empty agg-shaped node
// (2048 blocks x 256 thr, 1 int store/block). Marginal dur_us = pure
// per-dispatch overhead+ramp for an agg-class grid. Decides round 18:
// small delta -> attack k_agg work; big delta -> declare structural plateau.
// ============================================================================

// Problem constants (from setup_inputs): B=8, N=1024, E=16384, Din=128, U=128
#define B_   8
#define N_   1024
#define E_   16384
#define DIN_ 128
#define U_   128
#define CAP_ 64     // bucket capacity per node; deg ~ Poisson(16), P(>64) ~ 1e-20

// ---------------------------------------------------------------------------
// K1 (identical to r11): support = x @ kernel + zero counts. XCD-swizzled.
__global__ __launch_bounds__(256) void k_support(
    const float* __restrict__ x, const float* __restrict__ kern,
    float* __restrict__ support, int* __restrict__ counts) {
    const int tid = threadIdx.x;
    const int u = tid & 127;
    const int h = tid >> 7;                     // 0/1: rows h*8 .. h*8+7
    const int bb = blockIdx.x & 7;              // batch -> XCD bb
    const int rc = blockIdx.x >> 3;             // row chunk 0..63
    const int row0 = bb * N_ + rc * 16;         // global row base
    if (tid < 16) counts[row0 + tid] = 0;       // zero this chunk's counters
    __shared__ float xs[16][DIN_];
    const float4* xsrc = (const float4*)(x + (size_t)row0 * DIN_);
    #pragma unroll
    for (int i = 0; i < 2; ++i)                 // 512 float4 = 16x128 floats
        ((float4*)xs)[i * 256 + tid] = xsrc[i * 256 + tid];
    __syncthreads();
    float acc[8] = {0.f,0.f,0.f,0.f,0.f,0.f,0.f,0.f};
    #pragma unroll 4
    for (int d = 0; d < DIN_; ++d) {
        float k = kern[d * U_ + u];             // coalesced, L2-resident
        #pragma unroll
        for (int r = 0; r < 8; ++r) acc[r] = fmaf(xs[h*8+r][d], k, acc[r]);
    }
    #pragma unroll
    for (int r = 0; r < 8; ++r)
        support[(size_t)(row0 + h*8 + r) * U_ + u] = acc[r];
}

// ---------------------------------------------------------------------------
// K2 (identical to r11): one edge pass: count + bucket-place. XCD-swizzled.
__global__ __launch_bounds__(256) void k_fill(
    const int* __restrict__ edge_index, const int* __restrict__ edge_mask,
    int* __restrict__ counts, unsigned short* __restrict__ bucket) {
    const int b     = blockIdx.x & 7;                // batch -> XCD b
    const int chunk = blockIdx.x >> 3;               // 0..63
    const int e     = chunk * 256 + threadIdx.x;     // edge within batch
    if (edge_mask[(size_t)b * E_ + e] != 0) {
        const int* p = edge_index + (size_t)b * 2 * E_;
        int src = min(max(p[e], 0), N_ - 1);
        int dst = min(max(p[E_ + e], 0), N_ - 1);
        int bn = b * N_ + dst;
        int pos = atomicAdd(&counts[bn], 1);
        if (pos < CAP_) bucket[(size_t)bn * CAP_ + pos] = (unsigned short)src;
    }
}

// ---------------------------------------------------------------------------
// K3 (identical to r11): per-node aggregation, 2 nodes/block, XCD-swizzled.
__global__ __launch_bounds__(256) void k_agg(
    const float* __restrict__ support, const int* __restrict__ node_mask,
    const int* __restrict__ counts, const unsigned short* __restrict__ bucket,
    const float* __restrict__ bias, float* __restrict__ out) {
    const int bi  = blockIdx.x;                     // 0..4095
    const int swz = (bi & 7) * 512 + (bi >> 3);     // batch-major block index
    const int h   = threadIdx.x >> 7;
    const int u   = threadIdx.x & 127;
    const int bn  = swz * 2 + h;                    // b*N_ + n
    const int b   = bn >> 10;                       // / N_

    __shared__ int2 sp[2][CAP_];                    // {global row, isd_m bits}

    int nm = node_mask[bn];
    int cnt_true = counts[bn];
    int cnt = min(cnt_true, CAP_);
    float isd_n = rsqrtf(fmaxf((float)cnt_true + (nm ? 1.0f : 0.0f), 1e-6f));
    const unsigned short* bk = bucket + (size_t)bn * CAP_;

    if (u < cnt) {                                  // parallel weight precompute
        int m  = bk[u];
        int gm = b * N_ + m;
        float w = rsqrtf(fmaxf((float)counts[gm] + (node_mask[gm] ? 1.0f : 0.0f), 1e-6f));
        sp[h][u] = make_int2(gm, __float_as_int(w));
    }
    __syncthreads();

    float bs = bias[u];
    float acc = nm ? isd_n * support[(size_t)bn * U_ + u] : 0.f;
    #pragma unroll 4
    for (int t = 0; t < cnt; ++t) {
        int2 p = sp[h][t];                          // LDS broadcast
        acc = fmaf(__int_as_float(p.y), support[(size_t)p.x * U_ + u], acc);
    }
    out[(size_t)bn * U_ + u] = nm ? fmaf(isd_n, acc, bs) : 0.f;
}

// ---------------------------------------------------------------------------
// PROBE: empty agg-shaped node. 2048 blocks x 256 threads, one int store per
// block into unused scratch. Marginal cost = dispatch + ramp, zero work.
__global__ __launch_bounds__(256) void k_dummy(int* __restrict__ scratch) {
    if (threadIdx.x == 0) scratch[blockIdx.x] = (int)blockIdx.x;
}

// ---------------------------------------------------------------------------
extern "C" void kernel_launch(void* const* d_in, const int* in_sizes, int n_in,
                              void* d_out, int out_size, void* d_ws, size_t ws_size,
                              hipStream_t stream) {
    const float* x         = (const float*)d_in[0];
    const int*   node_mask = (const int*)d_in[1];
    const int*   edge_index= (const int*)d_in[2];
    const int*   edge_mask = (const int*)d_in[3];
    const float* kern      = (const float*)d_in[4];
    const float* bias      = (const float*)d_in[5];
    float*       out       = (float*)d_out;

    char* ws = (char*)d_ws;
    size_t off = 0;
    float*          support = (float*)(ws + off);          off += (size_t)B_ * N_ * U_ * sizeof(float);
    int*            counts  = (int*)(ws + off);            off += (size_t)B_ * N_ * sizeof(int);
    unsigned short* bucket  = (unsigned short*)(ws + off); off += (size_t)B_ * N_ * CAP_ * sizeof(unsigned short);
    int*            scratch = (int*)(ws + off);            off += 2048 * sizeof(int);

    k_support<<<B_ * N_ / 16, 256, 0, stream>>>(x, kern, support, counts);
    k_fill<<<B_ * E_ / 256, 256, 0, stream>>>(edge_index, edge_mask, counts, bucket);
    k_agg<<<B_ * N_ / 2, 256, 0, stream>>>(support, node_mask, counts, bucket, bias, out);
    k_dummy<<<2048, 256, 0, stream>>>(scratch);   // PROBE node
}

// Round 18
// 28.710 us; speedup vs baseline: 1.1154x; 1.0743x over previous
//
#include <hip/hip_runtime.h>

// Problem constants (from setup_inputs): B=8, N=1024, E=16384, Din=128, U=128
#define B_   8
#define N_   1024
#define E_   16384
#define DIN_ 128
#define U_   128
#define CAP_ 64     // bucket capacity per node; deg ~ Poisson(16), P(>64) ~ 1e-20

// ---------------------------------------------------------------------------
// K1 (identical to r11): support = x @ kernel + zero counts. XCD-swizzled.
__global__ __launch_bounds__(256) void k_support(
    const float* __restrict__ x, const float* __restrict__ kern,
    float* __restrict__ support, int* __restrict__ counts) {
    const int tid = threadIdx.x;
    const int u = tid & 127;
    const int h = tid >> 7;                     // 0/1: rows h*8 .. h*8+7
    const int bb = blockIdx.x & 7;              // batch -> XCD bb
    const int rc = blockIdx.x >> 3;             // row chunk 0..63
    const int row0 = bb * N_ + rc * 16;         // global row base
    if (tid < 16) counts[row0 + tid] = 0;       // zero this chunk's counters
    __shared__ float xs[16][DIN_];
    const float4* xsrc = (const float4*)(x + (size_t)row0 * DIN_);
    #pragma unroll
    for (int i = 0; i < 2; ++i)                 // 512 float4 = 16x128 floats
        ((float4*)xs)[i * 256 + tid] = xsrc[i * 256 + tid];
    __syncthreads();
    float acc[8] = {0.f,0.f,0.f,0.f,0.f,0.f,0.f,0.f};
    #pragma unroll 4
    for (int d = 0; d < DIN_; ++d) {
        float k = kern[d * U_ + u];             // coalesced, L2-resident
        #pragma unroll
        for (int r = 0; r < 8; ++r) acc[r] = fmaf(xs[h*8+r][d], k, acc[r]);
    }
    #pragma unroll
    for (int r = 0; r < 8; ++r)
        support[(size_t)(row0 + h*8 + r) * U_ + u] = acc[r];
}

// ---------------------------------------------------------------------------
// K2 (identical to r11): one edge pass: count + bucket-place. XCD-swizzled.
__global__ __launch_bounds__(256) void k_fill(
    const int* __restrict__ edge_index, const int* __restrict__ edge_mask,
    int* __restrict__ counts, unsigned short* __restrict__ bucket) {
    const int b     = blockIdx.x & 7;                // batch -> XCD b
    const int chunk = blockIdx.x >> 3;               // 0..63
    const int e     = chunk * 256 + threadIdx.x;     // edge within batch
    if (edge_mask[(size_t)b * E_ + e] != 0) {
        const int* p = edge_index + (size_t)b * 2 * E_;
        int src = min(max(p[e], 0), N_ - 1);
        int dst = min(max(p[E_ + e], 0), N_ - 1);
        int bn = b * N_ + dst;
        int pos = atomicAdd(&counts[bn], 1);
        if (pos < CAP_) bucket[(size_t)bn * CAP_ + pos] = (unsigned short)src;
    }
}

// ---------------------------------------------------------------------------
// K3: per-node aggregation — SINGLE CHANGE vs r11: inner loop restructured
// into chunked prefetch of 8. sp is padded to a multiple of 8 with
// zero-weight entries (row = bn, safe to load), so the loop is branch-free
// with fixed 8-wide unrolls: 8 independent L2 loads in flight per chunk
// (vs compiler's ~4 with the old unroll-4 dependent chain). Grid, swizzle,
// weight precompute all r11-identical.
__global__ __launch_bounds__(256) void k_agg(
    const float* __restrict__ support, const int* __restrict__ node_mask,
    const int* __restrict__ counts, const unsigned short* __restrict__ bucket,
    const float* __restrict__ bias, float* __restrict__ out) {
    const int bi  = blockIdx.x;                     // 0..4095
    const int swz = (bi & 7) * 512 + (bi >> 3);     // batch-major block index
    const int h   = threadIdx.x >> 7;
    const int u   = threadIdx.x & 127;
    const int bn  = swz * 2 + h;                    // b*N_ + n
    const int b   = bn >> 10;                       // / N_

    __shared__ int2 sp[2][CAP_];                    // {global row, isd_m bits}

    int nm = node_mask[bn];
    int cnt_true = counts[bn];
    int cnt = min(cnt_true, CAP_);
    int cntp = (cnt + 7) & ~7;                      // padded to multiple of 8
    float isd_n = rsqrtf(fmaxf((float)cnt_true + (nm ? 1.0f : 0.0f), 1e-6f));
    const unsigned short* bk = bucket + (size_t)bn * CAP_;

    if (u < cnt) {                                  // parallel weight precompute
        int m  = bk[u];
        int gm = b * N_ + m;
        float w = rsqrtf(fmaxf((float)counts[gm] + (node_mask[gm] ? 1.0f : 0.0f), 1e-6f));
        sp[h][u] = make_int2(gm, __float_as_int(w));
    } else if (u < cntp) {
        sp[h][u] = make_int2(bn, 0);                // zero-weight pad entry
    }
    __syncthreads();

    float bs = bias[u];
    float acc = nm ? isd_n * support[(size_t)bn * U_ + u] : 0.f;
    for (int t = 0; t < cntp; t += 8) {
        float v[8], w[8];
        #pragma unroll
        for (int i = 0; i < 8; ++i) {               // 8 loads issued back-to-back
            int2 p = sp[h][t + i];                  // LDS broadcast
            w[i] = __int_as_float(p.y);
            v[i] = support[(size_t)p.x * U_ + u];   // independent L2 loads
        }
        #pragma unroll
        for (int i = 0; i < 8; ++i)
            acc = fmaf(w[i], v[i], acc);
    }
    out[(size_t)bn * U_ + u] = nm ? fmaf(isd_n, acc, bs) : 0.f;
}

// ---------------------------------------------------------------------------
extern "C" void kernel_launch(void* const* d_in, const int* in_sizes, int n_in,
                              void* d_out, int out_size, void* d_ws, size_t ws_size,
                              hipStream_t stream) {
    const float* x         = (const float*)d_in[0];
    const int*   node_mask = (const int*)d_in[1];
    const int*   edge_index= (const int*)d_in[2];
    const int*   edge_mask = (const int*)d_in[3];
    const float* kern      = (const float*)d_in[4];
    const float* bias      = (const float*)d_in[5];
    float*       out       = (float*)d_out;

    char* ws = (char*)d_ws;
    size_t off = 0;
    float*          support = (float*)(ws + off);          off += (size_t)B_ * N_ * U_ * sizeof(float);
    int*            counts  = (int*)(ws + off);            off += (size_t)B_ * N_ * sizeof(int);
    unsigned short* bucket  = (unsigned short*)(ws + off); off += (size_t)B_ * N_ * CAP_ * sizeof(unsigned short);

    k_support<<<B_ * N_ / 16, 256, 0, stream>>>(x, kern, support, counts);
    k_fill<<<B_ * E_ / 256, 256, 0, stream>>>(edge_index, edge_mask, counts, bucket);
    k_agg<<<B_ * N_ / 2, 256, 0, stream>>>(support, node_mask, counts, bucket, bias, out);
}